// Round 18
// baseline (138.517 us; speedup 1.0000x reference)
//
#include <hip/hip_runtime.h>

#define BB 4096
#define TT 256
#define FF 32
#define HH 6

#define DPP_XOR1 0xB1   // quad_perm(1,0,3,2)
#define DPP_XOR2 0x4E   // quad_perm(2,3,0,1)
#define DPP_XOR3 0x1B   // quad_perm(3,2,1,0)
#define DPP_HALF 0x141  // row_half_mirror = xor 7 within 8-lane half-rows

__device__ __forceinline__ float fast_rcp(float x) { return __builtin_amdgcn_rcpf(x); }
__device__ __forceinline__ float sigmoidf(float x) { return fast_rcp(1.0f + __expf(-x)); }

template <int CTRL>
__device__ __forceinline__ float dppf(float x) {
    return __int_as_float(__builtin_amdgcn_update_dpp(
        0, __float_as_int(x), CTRL, 0xF, 0xF, true));
}
__device__ __forceinline__ float dpp_xor4(float x) {
    return dppf<DPP_HALF>(dppf<DPP_XOR3>(x));
}

typedef const __attribute__((address_space(1))) void* gas_ptr;
typedef __attribute__((address_space(3))) void* las_ptr;
__device__ __forceinline__ void gl_lds16(const float* g, float* l) {
    __builtin_amdgcn_global_load_lds((gas_ptr)g, (las_ptr)l, 16, 0, 0);
}

// K1 v2: 4 lanes per (b,t), interleaved ownership (verified R13-R17 numerics),
// PHA split into two 16-column halves so peak live set = own[8]+part[16] ~ 26
// regs -> fits the allocator's budget with feature-outer scheduling (Wa rows
// read once per half, no remat).
__global__ __launch_bounds__(256, 4) void k_attn_xz(
    const float* __restrict__ x, const float* __restrict__ Wa, const float* __restrict__ ba,
    const float* __restrict__ Wl, const float* __restrict__ bl, float* __restrict__ xz)
{
    __shared__ __align__(16) float wa_s[FF * 36];   // rows padded 32->36 floats
    __shared__ __align__(16) float wl_s[FF * 28];   // rows padded 24->28 floats
    const int lt = threadIdx.x;

    {
        const float4 v = *(const float4*)(Wa + lt * 4);
        *(float4*)(wa_s + (lt >> 3) * 36 + (lt & 7) * 4) = v;
        if (lt < 192) {
            const float4 w = *(const float4*)(Wl + lt * 4);
            *(float4*)(wl_s + (lt / 6) * 28 + (lt % 6) * 4) = w;
        }
    }
    __syncthreads();

    const int tid = blockIdx.x * 256 + threadIdx.x;
    const int item = tid >> 2;
    const int q = tid & 3;
    const bool b0 = (q & 1) != 0;
    const bool b1 = (q & 2) != 0;
    const float* xp = x + (size_t)item * FF;

    float own[8];
#pragma unroll
    for (int i = 0; i < 8; ++i) own[i] = xp[4 * i + q];

    float dotv[8];

    // reduce-scatter a 16-col half: lane q gets col (C0 + 4*ci + q) at dotv[DST+ci]
#define RSG_H(CI, DST) { \
        const float p0 = part[4*(CI)+0], p1 = part[4*(CI)+1]; \
        const float p2 = part[4*(CI)+2], p3 = part[4*(CI)+3]; \
        const float v01 = b0 ? p1 : p0, u01 = b0 ? p0 : p1; \
        const float v23 = b0 ? p3 : p2, u23 = b0 ? p2 : p3; \
        const float r01 = v01 + dppf<DPP_XOR1>(u01); \
        const float r23 = v23 + dppf<DPP_XOR1>(u23); \
        const float vv = b1 ? r23 : r01, uu = b1 ? r01 : r23; \
        dotv[(DST)+(CI)] = vv + dppf<DPP_XOR2>(uu); }

    {   // half 0: columns 0..15
        float part[16];
#pragma unroll
        for (int c = 0; c < 16; ++c) part[c] = 0.0f;
#define PHA0(I) { \
        const float xi = own[I]; \
        const float* wr = wa_s + (4 * (I) + q) * 36; \
        _Pragma("unroll") \
        for (int cc = 0; cc < 4; ++cc) { \
            const float4 w = *(const float4*)(wr + cc * 4); \
            part[cc*4+0] = fmaf(xi, w.x, part[cc*4+0]); \
            part[cc*4+1] = fmaf(xi, w.y, part[cc*4+1]); \
            part[cc*4+2] = fmaf(xi, w.z, part[cc*4+2]); \
            part[cc*4+3] = fmaf(xi, w.w, part[cc*4+3]); \
        } }
        PHA0(0) PHA0(1) PHA0(2) PHA0(3) PHA0(4) PHA0(5) PHA0(6) PHA0(7)
#undef PHA0
        RSG_H(0, 0) RSG_H(1, 0) RSG_H(2, 0) RSG_H(3, 0)
    }
    {   // half 1: columns 16..31
        float part[16];
#pragma unroll
        for (int c = 0; c < 16; ++c) part[c] = 0.0f;
#define PHA1(I) { \
        const float xi = own[I]; \
        const float* wr = wa_s + (4 * (I) + q) * 36 + 16; \
        _Pragma("unroll") \
        for (int cc = 0; cc < 4; ++cc) { \
            const float4 w = *(const float4*)(wr + cc * 4); \
            part[cc*4+0] = fmaf(xi, w.x, part[cc*4+0]); \
            part[cc*4+1] = fmaf(xi, w.y, part[cc*4+1]); \
            part[cc*4+2] = fmaf(xi, w.z, part[cc*4+2]); \
            part[cc*4+3] = fmaf(xi, w.w, part[cc*4+3]); \
        } }
        PHA1(0) PHA1(1) PHA1(2) PHA1(3) PHA1(4) PHA1(5) PHA1(6) PHA1(7)
#undef PHA1
        RSG_H(0, 4) RSG_H(1, 4) RSG_H(2, 4) RSG_H(3, 4)
    }
#undef RSG_H

    // exp (no max-sub: |s| small, fp32 safe — verified R9-R17) + quad sum
    float e[8];
    float sum = 0.0f;
#pragma unroll
    for (int i = 0; i < 8; ++i) {
        e[i] = __expf(dotv[i] + ba[4 * i + q]);
        sum += e[i];
    }
    sum += dppf<DPP_XOR1>(sum);
    sum += dppf<DPP_XOR2>(sum);

    float acc[24];
#pragma unroll
    for (int g = 0; g < 24; ++g) acc[g] = 0.0f;

#define PHB(I) { \
        const float pp = own[I] * e[I]; \
        const float* wr = wl_s + (4 * (I) + q) * 28; \
        _Pragma("unroll") \
        for (int gc = 0; gc < 6; ++gc) { \
            const float4 w = *(const float4*)(wr + gc * 4); \
            acc[gc*4+0] = fmaf(pp, w.x, acc[gc*4+0]); \
            acc[gc*4+1] = fmaf(pp, w.y, acc[gc*4+1]); \
            acc[gc*4+2] = fmaf(pp, w.z, acc[gc*4+2]); \
            acc[gc*4+3] = fmaf(pp, w.w, acc[gc*4+3]); \
        } }
    PHB(0) PHB(1) PHB(2) PHB(3) PHB(4) PHB(5) PHB(6) PHB(7)
#undef PHB

#pragma unroll
    for (int g = 0; g < 24; ++g) acc[g] += dppf<DPP_XOR1>(acc[g]);
#pragma unroll
    for (int g = 0; g < 24; ++g) acc[g] += dppf<DPP_XOR2>(acc[g]);

    const float r = fast_rcp(sum);

    // epilogue (verified): transpose gate-major -> [unit][i,f,g,o]
    float* op = xz + (size_t)item * 24;
    {
        const float ai = (q == 0) ? acc[0]  : (q == 1) ? acc[1]  : (q == 2) ? acc[2]  : acc[3];
        const float af = (q == 0) ? acc[6]  : (q == 1) ? acc[7]  : (q == 2) ? acc[8]  : acc[9];
        const float ag = (q == 0) ? acc[12] : (q == 1) ? acc[13] : (q == 2) ? acc[14] : acc[15];
        const float ao = (q == 0) ? acc[18] : (q == 1) ? acc[19] : (q == 2) ? acc[20] : acc[21];
        float4 o;
        o.x = fmaf(ai, r, bl[0  + q]);
        o.y = fmaf(af, r, bl[6  + q]);
        o.z = fmaf(ag, r, bl[12 + q]);
        o.w = fmaf(ao, r, bl[18 + q]);
        *(float4*)(op + q * 4) = o;
    }
    if (q < 2) {
        const int jp = 4 + q;
        const float ai = (q == 0) ? acc[4]  : acc[5];
        const float af = (q == 0) ? acc[10] : acc[11];
        const float ag = (q == 0) ? acc[16] : acc[17];
        const float ao = (q == 0) ? acc[22] : acc[23];
        float4 o;
        o.x = fmaf(ai, r, bl[0  + jp]);
        o.y = fmaf(af, r, bl[6  + jp]);
        o.z = fmaf(ag, r, bl[12 + jp]);
        o.w = fmaf(ao, r, bl[18 + jp]);
        *(float4*)(op + jp * 4) = o;
    }
}

// One LSTM step (defer-max c-softmax, verified). Returns hn.
__device__ __forceinline__ float chain_step(
    float hl[8], float& c, float& r2,
    const float Ui[8], const float Uf[8], const float Ug[8], const float Uo[8],
    const float4 z4, const bool real)
{
    float di0 = hl[0]*Ui[0], di1 = hl[4]*Ui[4];
    float df0 = hl[0]*Uf[0], df1 = hl[4]*Uf[4];
    float dg0 = hl[0]*Ug[0], dg1 = hl[4]*Ug[4];
    float dq0 = hl[0]*Uo[0], dq1 = hl[4]*Uo[4];
#pragma unroll
    for (int m = 1; m < 4; ++m) {
        di0 = fmaf(hl[m], Ui[m], di0); di1 = fmaf(hl[m+4], Ui[m+4], di1);
        df0 = fmaf(hl[m], Uf[m], df0); df1 = fmaf(hl[m+4], Uf[m+4], df1);
        dg0 = fmaf(hl[m], Ug[m], dg0); dg1 = fmaf(hl[m+4], Ug[m+4], dg1);
        dq0 = fmaf(hl[m], Uo[m], dq0); dq1 = fmaf(hl[m+4], Uo[m+4], dq1);
    }
    const float zi = fmaf(di0 + di1, r2, z4.x);
    const float zf = fmaf(df0 + df1, r2, z4.y);
    const float zg = fmaf(dg0 + dg1, r2, z4.z);
    const float zo = fmaf(dq0 + dq1, r2, z4.w);

    const float iv = sigmoidf(zi);
    const float fv = sigmoidf(zf);
    const float ov = sigmoidf(zo);

    const float eg = real ? __expf(zg) : 0.0f;
    float s1 = eg;
    s1 += dppf<DPP_XOR1>(s1);
    s1 += dppf<DPP_XOR2>(s1);
    s1 += dpp_xor4(s1);
    c = fmaf(fv, c, (iv * eg) * fast_rcp(s1));

    const float ec = real ? __expf(c) : 0.0f;   // defer-max (uniform exp(-m) cancels)
    float s2 = ec;
    s2 += dppf<DPP_XOR1>(s2);
    s2 += dppf<DPP_XOR2>(s2);
    s2 += dpp_xor4(s2);

    const float ovec = ov * ec;
    hl[0] = ovec;
    hl[1] = dppf<DPP_XOR1>(ovec);
    hl[2] = dppf<DPP_XOR2>(ovec);
    hl[3] = dppf<DPP_XOR3>(ovec);
    const float h7 = dppf<DPP_HALF>(ovec);
    hl[7] = h7;
    hl[6] = dppf<DPP_XOR1>(h7);
    hl[5] = dppf<DPP_XOR2>(h7);
    hl[4] = dppf<DPP_XOR3>(h7);
    r2 = fast_rcp(s2);
    return ovec * r2;
}

// K2 (byte-identical to R17, verified): deferred-y scan + parallel dense(10).
__global__ __launch_bounds__(64, 1) void k_scan(
    const float* __restrict__ xz, const float* __restrict__ Ul,
    const float* __restrict__ W10, const float* __restrict__ b10,
    const float* __restrict__ Wo, const float* __restrict__ bo,
    float* __restrict__ out)
{
    const int lane = threadIdx.x;
    const int j = lane & 7;
    const int grp = lane >> 3;
    const int b = blockIdx.x * 8 + grp;
    const bool real = (j < HH);

    __shared__ __align__(1024) float ring[16 * 256];   // 16 steps x 1KB
    __shared__ __align__(16) float h_lds[TT * 64];     // 64KB: h[t][lane]

    float Ui[8], Uf[8], Ug[8], Uo[8];
#pragma unroll
    for (int m = 0; m < 8; ++m) {
        const int src = j ^ m;
        const bool ok = real && (src < HH);
        const float* row = Ul + (ok ? src : 0) * 24;
        Ui[m] = ok ? row[0  + j] : 0.0f;
        Uf[m] = ok ? row[6  + j] : 0.0f;
        Ug[m] = ok ? row[12 + j] : 0.0f;
        Uo[m] = ok ? row[18 + j] : 0.0f;
    }

    float hl[8];
    float r2 = 1.0f, c = 0.0f;
#pragma unroll
    for (int m = 0; m < 8; ++m) hl[m] = 0.0f;

    const float* gsrc = xz + (size_t)b * (TT * 24) + j * 4;

#define STAGE(G) { \
        const float* s_ = gsrc + (size_t)((G) * 8) * 24; \
        float* lb_ = ring + (((G) * 8) & 15) * 256; \
        _Pragma("unroll") \
        for (int k_ = 0; k_ < 8; ++k_) gl_lds16(s_ + k_ * 24, lb_ + k_ * 256); }

    STAGE(0) STAGE(1)
    asm volatile("s_waitcnt vmcnt(8)" ::: "memory");   // group 0 resident

    float4 zcur = *(const float4*)(ring + 0 * 256 + lane * 4);
    float4 zn1  = *(const float4*)(ring + 1 * 256 + lane * 4);

#define STEP(K) { \
        const float4 zn2 = *(const float4*)(ring + (((sb + (K) + 2) & 15) << 8) + lane * 4); \
        const float hn = chain_step(hl, c, r2, Ui, Uf, Ug, Uo, zcur, real); \
        h_lds[((t0 + (K)) << 6) + lane] = hn; \
        zcur = zn1; zn1 = zn2; }

#pragma unroll 1
    for (int gi = 0; gi < 32; ++gi) {
        const int t0 = gi * 8;
        const int sb = (gi & 1) * 8;
        STEP(0) STEP(1) STEP(2) STEP(3) STEP(4) STEP(5)
        if (gi < 30) {
            STAGE(gi + 2)
            asm volatile("s_waitcnt vmcnt(8)" ::: "memory");
        } else if (gi == 30) {
            asm volatile("s_waitcnt vmcnt(0)" ::: "memory");   // group 31 resident
        }
        STEP(6) STEP(7)
    }
#undef STEP
#undef STAGE

    asm volatile("s_waitcnt lgkmcnt(0)" ::: "memory");
    __builtin_amdgcn_sched_barrier(0);

    // Phase 2: y[p] = sum over my t-slice {t = 8*tb + j} of sum_u h[t][u]*W10[t*6+u][p]
    float yl[10];
#pragma unroll
    for (int p = 0; p < 10; ++p) yl[p] = 0.0f;

#pragma unroll 2
    for (int tb = 0; tb < 32; ++tb) {
        const int t = tb * 8 + j;
        const float* hb = h_lds + (t << 6) + (grp << 3);
        const float2 h01 = *(const float2*)(hb + 0);
        const float2 h23 = *(const float2*)(hb + 2);
        const float2 h45 = *(const float2*)(hb + 4);
        const float* wr = W10 + (size_t)t * 60;
#define ACCU(U, HV) { \
        const float2 w0 = *(const float2*)(wr + (U) * 10 + 0); \
        const float2 w1 = *(const float2*)(wr + (U) * 10 + 2); \
        const float2 w2 = *(const float2*)(wr + (U) * 10 + 4); \
        const float2 w3 = *(const float2*)(wr + (U) * 10 + 6); \
        const float2 w4 = *(const float2*)(wr + (U) * 10 + 8); \
        yl[0] = fmaf(HV, w0.x, yl[0]); yl[1] = fmaf(HV, w0.y, yl[1]); \
        yl[2] = fmaf(HV, w1.x, yl[2]); yl[3] = fmaf(HV, w1.y, yl[3]); \
        yl[4] = fmaf(HV, w2.x, yl[4]); yl[5] = fmaf(HV, w2.y, yl[5]); \
        yl[6] = fmaf(HV, w3.x, yl[6]); yl[7] = fmaf(HV, w3.y, yl[7]); \
        yl[8] = fmaf(HV, w4.x, yl[8]); yl[9] = fmaf(HV, w4.y, yl[9]); }
        ACCU(0, h01.x) ACCU(1, h01.y) ACCU(2, h23.x)
        ACCU(3, h23.y) ACCU(4, h45.x) ACCU(5, h45.y)
#undef ACCU
    }

#pragma unroll
    for (int p = 0; p < 10; ++p) {
        float v = yl[p];
        v += dppf<DPP_XOR1>(v);
        v += dppf<DPP_XOR2>(v);
        v += dpp_xor4(v);
        yl[p] = v;
    }

    float o8 = bo[j];
#pragma unroll
    for (int p = 0; p < 10; ++p) o8 = fmaf(yl[p] + b10[p], Wo[p * 8 + j], o8);
    out[(size_t)b * 8 + j] = o8;
}

extern "C" void kernel_launch(void* const* d_in, const int* in_sizes, int n_in,
                              void* d_out, int out_size, void* d_ws, size_t ws_size,
                              hipStream_t stream) {
    const float* x   = (const float*)d_in[0];
    const float* Wa  = (const float*)d_in[1];
    const float* ba  = (const float*)d_in[2];
    const float* Wl  = (const float*)d_in[3];
    const float* Ul  = (const float*)d_in[4];
    const float* bl  = (const float*)d_in[5];
    const float* W10 = (const float*)d_in[6];
    const float* b10 = (const float*)d_in[7];
    const float* Wo  = (const float*)d_in[8];
    const float* bo  = (const float*)d_in[9];
    float* out = (float*)d_out;
    float* xz  = (float*)d_ws;   // BB*TT*24*4 = 96 MiB

    hipLaunchKernelGGL(k_attn_xz, dim3(BB * TT * 4 / 256), dim3(256), 0, stream,
                       x, Wa, ba, Wl, bl, xz);
    hipLaunchKernelGGL(k_scan, dim3(BB / 8), dim3(64), 0, stream,
                       xz, Ul, W10, b10, Wo, bo, out);
}

// Round 19
// 134.571 us; speedup vs baseline: 1.0293x; 1.0293x over previous
//
#include <hip/hip_runtime.h>

#define BB 4096
#define TT 256
#define FF 32
#define HH 6

#define DPP_XOR1 0xB1   // quad_perm(1,0,3,2)
#define DPP_XOR2 0x4E   // quad_perm(2,3,0,1)
#define DPP_XOR3 0x1B   // quad_perm(3,2,1,0)
#define DPP_HALF 0x141  // row_half_mirror = xor 7 within 8-lane half-rows

__device__ __forceinline__ float fast_rcp(float x) { return __builtin_amdgcn_rcpf(x); }
__device__ __forceinline__ float sigmoidf(float x) { return fast_rcp(1.0f + __expf(-x)); }

template <int CTRL>
__device__ __forceinline__ float dppf(float x) {
    return __int_as_float(__builtin_amdgcn_update_dpp(
        0, __float_as_int(x), CTRL, 0xF, 0xF, true));
}
__device__ __forceinline__ float dpp_xor4(float x) {
    return dppf<DPP_HALF>(dppf<DPP_XOR3>(x));
}

typedef const __attribute__((address_space(1))) void* gas_ptr;
typedef __attribute__((address_space(3))) void* las_ptr;
__device__ __forceinline__ void gl_lds16(const float* g, float* l) {
    __builtin_amdgcn_global_load_lds((gas_ptr)g, (las_ptr)l, 16, 0, 0);
}

// K1 v3: ITEMS=2 per quad. K1 was LDS-BW-bound (7KB weights read per item,
// 93us wall); each weight float4 now feeds TWO items' FMAs -> traffic/item
// halved. Numerics identical to verified v2 (RSG butterfly, no-max-sub exp,
// cndmask transpose epilogue), duplicated per item.
__global__ __launch_bounds__(256, 1) void k_attn_xz(
    const float* __restrict__ x, const float* __restrict__ Wa, const float* __restrict__ ba,
    const float* __restrict__ Wl, const float* __restrict__ bl, float* __restrict__ xz)
{
    __shared__ __align__(16) float wa_s[FF * 36];   // rows padded 32->36 floats
    __shared__ __align__(16) float wl_s[FF * 28];   // rows padded 24->28 floats
    const int lt = threadIdx.x;

    {
        const float4 v = *(const float4*)(Wa + lt * 4);
        *(float4*)(wa_s + (lt >> 3) * 36 + (lt & 7) * 4) = v;
        if (lt < 192) {
            const float4 w = *(const float4*)(Wl + lt * 4);
            *(float4*)(wl_s + (lt / 6) * 28 + (lt % 6) * 4) = w;
        }
    }
    __syncthreads();

    const int tid = blockIdx.x * 256 + threadIdx.x;
    const int itemA = (tid >> 2) * 2;
    const int itemB = itemA + 1;
    const int q = tid & 3;
    const bool b0 = (q & 1) != 0;
    const bool b1 = (q & 2) != 0;
    const float* xpA = x + (size_t)itemA * FF;
    const float* xpB = x + (size_t)itemB * FF;

    float ownA[8], ownB[8];
#pragma unroll
    for (int i = 0; i < 8; ++i) { ownA[i] = xpA[4 * i + q]; ownB[i] = xpB[4 * i + q]; }

    float dotvA[8], dotvB[8];

#define RSG_H(P, CI, DST, DV) { \
        const float p0 = P[4*(CI)+0], p1 = P[4*(CI)+1]; \
        const float p2 = P[4*(CI)+2], p3 = P[4*(CI)+3]; \
        const float v01 = b0 ? p1 : p0, u01 = b0 ? p0 : p1; \
        const float v23 = b0 ? p3 : p2, u23 = b0 ? p2 : p3; \
        const float r01 = v01 + dppf<DPP_XOR1>(u01); \
        const float r23 = v23 + dppf<DPP_XOR1>(u23); \
        const float vv = b1 ? r23 : r01, uu = b1 ? r01 : r23; \
        DV[(DST)+(CI)] = vv + dppf<DPP_XOR2>(uu); }

#define PHA_HALF(OFS, DST)                                              \
    {                                                                   \
        float partA[16], partB[16];                                     \
        _Pragma("unroll")                                               \
        for (int c = 0; c < 16; ++c) { partA[c] = 0.0f; partB[c] = 0.0f; } \
        _Pragma("unroll")                                               \
        for (int I = 0; I < 8; ++I) {                                   \
            const float xa = ownA[I], xb = ownB[I];                     \
            const float* wr = wa_s + (4 * I + q) * 36 + (OFS);          \
            _Pragma("unroll")                                           \
            for (int cc = 0; cc < 4; ++cc) {                            \
                const float4 w = *(const float4*)(wr + cc * 4);         \
                partA[cc*4+0] = fmaf(xa, w.x, partA[cc*4+0]);           \
                partA[cc*4+1] = fmaf(xa, w.y, partA[cc*4+1]);           \
                partA[cc*4+2] = fmaf(xa, w.z, partA[cc*4+2]);           \
                partA[cc*4+3] = fmaf(xa, w.w, partA[cc*4+3]);           \
                partB[cc*4+0] = fmaf(xb, w.x, partB[cc*4+0]);           \
                partB[cc*4+1] = fmaf(xb, w.y, partB[cc*4+1]);           \
                partB[cc*4+2] = fmaf(xb, w.z, partB[cc*4+2]);           \
                partB[cc*4+3] = fmaf(xb, w.w, partB[cc*4+3]);           \
            }                                                           \
        }                                                               \
        RSG_H(partA, 0, DST, dotvA) RSG_H(partA, 1, DST, dotvA)         \
        RSG_H(partA, 2, DST, dotvA) RSG_H(partA, 3, DST, dotvA)         \
        RSG_H(partB, 0, DST, dotvB) RSG_H(partB, 1, DST, dotvB)         \
        RSG_H(partB, 2, DST, dotvB) RSG_H(partB, 3, DST, dotvB)         \
    }

    PHA_HALF(0, 0)    // columns 0..15  -> dotv[0..3]
    PHA_HALF(16, 4)   // columns 16..31 -> dotv[4..7]
#undef PHA_HALF
#undef RSG_H

    // exp (no max-sub, verified) + quad sums
    float eA[8], eB[8];
    float sumA = 0.0f, sumB = 0.0f;
#pragma unroll
    for (int i = 0; i < 8; ++i) {
        eA[i] = __expf(dotvA[i] + ba[4 * i + q]);
        sumA += eA[i];
        eB[i] = __expf(dotvB[i] + ba[4 * i + q]);
        sumB += eB[i];
    }
    sumA += dppf<DPP_XOR1>(sumA);
    sumA += dppf<DPP_XOR2>(sumA);
    sumB += dppf<DPP_XOR1>(sumB);
    sumB += dppf<DPP_XOR2>(sumB);

    float accA[24], accB[24];
#pragma unroll
    for (int g = 0; g < 24; ++g) { accA[g] = 0.0f; accB[g] = 0.0f; }

#pragma unroll
    for (int I = 0; I < 8; ++I) {
        const float pa = ownA[I] * eA[I];
        const float pb = ownB[I] * eB[I];
        const float* wr = wl_s + (4 * I + q) * 28;
#pragma unroll
        for (int gc = 0; gc < 6; ++gc) {
            const float4 w = *(const float4*)(wr + gc * 4);
            accA[gc*4+0] = fmaf(pa, w.x, accA[gc*4+0]);
            accA[gc*4+1] = fmaf(pa, w.y, accA[gc*4+1]);
            accA[gc*4+2] = fmaf(pa, w.z, accA[gc*4+2]);
            accA[gc*4+3] = fmaf(pa, w.w, accA[gc*4+3]);
            accB[gc*4+0] = fmaf(pb, w.x, accB[gc*4+0]);
            accB[gc*4+1] = fmaf(pb, w.y, accB[gc*4+1]);
            accB[gc*4+2] = fmaf(pb, w.z, accB[gc*4+2]);
            accB[gc*4+3] = fmaf(pb, w.w, accB[gc*4+3]);
        }
    }

#pragma unroll
    for (int g = 0; g < 24; ++g) accA[g] += dppf<DPP_XOR1>(accA[g]);
#pragma unroll
    for (int g = 0; g < 24; ++g) accA[g] += dppf<DPP_XOR2>(accA[g]);
#pragma unroll
    for (int g = 0; g < 24; ++g) accB[g] += dppf<DPP_XOR1>(accB[g]);
#pragma unroll
    for (int g = 0; g < 24; ++g) accB[g] += dppf<DPP_XOR2>(accB[g]);

    const float rA = fast_rcp(sumA);
    const float rB = fast_rcp(sumB);

    // epilogue (verified cndmask transpose), per item
#define EPI(ACC, R, ITEM)                                               \
    {                                                                   \
        float* op = xz + (size_t)(ITEM) * 24;                           \
        {                                                               \
            const float ai = (q == 0) ? ACC[0]  : (q == 1) ? ACC[1]  : (q == 2) ? ACC[2]  : ACC[3];  \
            const float af = (q == 0) ? ACC[6]  : (q == 1) ? ACC[7]  : (q == 2) ? ACC[8]  : ACC[9];  \
            const float ag = (q == 0) ? ACC[12] : (q == 1) ? ACC[13] : (q == 2) ? ACC[14] : ACC[15]; \
            const float ao = (q == 0) ? ACC[18] : (q == 1) ? ACC[19] : (q == 2) ? ACC[20] : ACC[21]; \
            float4 o;                                                   \
            o.x = fmaf(ai, R, bl[0  + q]);                              \
            o.y = fmaf(af, R, bl[6  + q]);                              \
            o.z = fmaf(ag, R, bl[12 + q]);                              \
            o.w = fmaf(ao, R, bl[18 + q]);                              \
            *(float4*)(op + q * 4) = o;                                 \
        }                                                               \
        if (q < 2) {                                                    \
            const int jp = 4 + q;                                       \
            const float ai = (q == 0) ? ACC[4]  : ACC[5];               \
            const float af = (q == 0) ? ACC[10] : ACC[11];              \
            const float ag = (q == 0) ? ACC[16] : ACC[17];              \
            const float ao = (q == 0) ? ACC[22] : ACC[23];              \
            float4 o;                                                   \
            o.x = fmaf(ai, R, bl[0  + jp]);                             \
            o.y = fmaf(af, R, bl[6  + jp]);                             \
            o.z = fmaf(ag, R, bl[12 + jp]);                             \
            o.w = fmaf(ao, R, bl[18 + jp]);                             \
            *(float4*)(op + jp * 4) = o;                                \
        }                                                               \
    }
    EPI(accA, rA, itemA)
    EPI(accB, rB, itemB)
#undef EPI
}

// One LSTM step (defer-max c-softmax, verified). Returns hn.
__device__ __forceinline__ float chain_step(
    float hl[8], float& c, float& r2,
    const float Ui[8], const float Uf[8], const float Ug[8], const float Uo[8],
    const float4 z4, const bool real)
{
    float di0 = hl[0]*Ui[0], di1 = hl[4]*Ui[4];
    float df0 = hl[0]*Uf[0], df1 = hl[4]*Uf[4];
    float dg0 = hl[0]*Ug[0], dg1 = hl[4]*Ug[4];
    float dq0 = hl[0]*Uo[0], dq1 = hl[4]*Uo[4];
#pragma unroll
    for (int m = 1; m < 4; ++m) {
        di0 = fmaf(hl[m], Ui[m], di0); di1 = fmaf(hl[m+4], Ui[m+4], di1);
        df0 = fmaf(hl[m], Uf[m], df0); df1 = fmaf(hl[m+4], Uf[m+4], df1);
        dg0 = fmaf(hl[m], Ug[m], dg0); dg1 = fmaf(hl[m+4], Ug[m+4], dg1);
        dq0 = fmaf(hl[m], Uo[m], dq0); dq1 = fmaf(hl[m+4], Uo[m+4], dq1);
    }
    const float zi = fmaf(di0 + di1, r2, z4.x);
    const float zf = fmaf(df0 + df1, r2, z4.y);
    const float zg = fmaf(dg0 + dg1, r2, z4.z);
    const float zo = fmaf(dq0 + dq1, r2, z4.w);

    const float iv = sigmoidf(zi);
    const float fv = sigmoidf(zf);
    const float ov = sigmoidf(zo);

    const float eg = real ? __expf(zg) : 0.0f;
    float s1 = eg;
    s1 += dppf<DPP_XOR1>(s1);
    s1 += dppf<DPP_XOR2>(s1);
    s1 += dpp_xor4(s1);
    c = fmaf(fv, c, (iv * eg) * fast_rcp(s1));

    const float ec = real ? __expf(c) : 0.0f;   // defer-max (uniform exp(-m) cancels)
    float s2 = ec;
    s2 += dppf<DPP_XOR1>(s2);
    s2 += dppf<DPP_XOR2>(s2);
    s2 += dpp_xor4(s2);

    const float ovec = ov * ec;
    hl[0] = ovec;
    hl[1] = dppf<DPP_XOR1>(ovec);
    hl[2] = dppf<DPP_XOR2>(ovec);
    hl[3] = dppf<DPP_XOR3>(ovec);
    const float h7 = dppf<DPP_HALF>(ovec);
    hl[7] = h7;
    hl[6] = dppf<DPP_XOR1>(h7);
    hl[5] = dppf<DPP_XOR2>(h7);
    hl[4] = dppf<DPP_XOR3>(h7);
    r2 = fast_rcp(s2);
    return ovec * r2;
}

// K2 (byte-identical to R17/R18, verified): deferred-y scan + parallel dense(10).
__global__ __launch_bounds__(64, 1) void k_scan(
    const float* __restrict__ xz, const float* __restrict__ Ul,
    const float* __restrict__ W10, const float* __restrict__ b10,
    const float* __restrict__ Wo, const float* __restrict__ bo,
    float* __restrict__ out)
{
    const int lane = threadIdx.x;
    const int j = lane & 7;
    const int grp = lane >> 3;
    const int b = blockIdx.x * 8 + grp;
    const bool real = (j < HH);

    __shared__ __align__(1024) float ring[16 * 256];   // 16 steps x 1KB
    __shared__ __align__(16) float h_lds[TT * 64];     // 64KB: h[t][lane]

    float Ui[8], Uf[8], Ug[8], Uo[8];
#pragma unroll
    for (int m = 0; m < 8; ++m) {
        const int src = j ^ m;
        const bool ok = real && (src < HH);
        const float* row = Ul + (ok ? src : 0) * 24;
        Ui[m] = ok ? row[0  + j] : 0.0f;
        Uf[m] = ok ? row[6  + j] : 0.0f;
        Ug[m] = ok ? row[12 + j] : 0.0f;
        Uo[m] = ok ? row[18 + j] : 0.0f;
    }

    float hl[8];
    float r2 = 1.0f, c = 0.0f;
#pragma unroll
    for (int m = 0; m < 8; ++m) hl[m] = 0.0f;

    const float* gsrc = xz + (size_t)b * (TT * 24) + j * 4;

#define STAGE(G) { \
        const float* s_ = gsrc + (size_t)((G) * 8) * 24; \
        float* lb_ = ring + (((G) * 8) & 15) * 256; \
        _Pragma("unroll") \
        for (int k_ = 0; k_ < 8; ++k_) gl_lds16(s_ + k_ * 24, lb_ + k_ * 256); }

    STAGE(0) STAGE(1)
    asm volatile("s_waitcnt vmcnt(8)" ::: "memory");   // group 0 resident

    float4 zcur = *(const float4*)(ring + 0 * 256 + lane * 4);
    float4 zn1  = *(const float4*)(ring + 1 * 256 + lane * 4);

#define STEP(K) { \
        const float4 zn2 = *(const float4*)(ring + (((sb + (K) + 2) & 15) << 8) + lane * 4); \
        const float hn = chain_step(hl, c, r2, Ui, Uf, Ug, Uo, zcur, real); \
        h_lds[((t0 + (K)) << 6) + lane] = hn; \
        zcur = zn1; zn1 = zn2; }

#pragma unroll 1
    for (int gi = 0; gi < 32; ++gi) {
        const int t0 = gi * 8;
        const int sb = (gi & 1) * 8;
        STEP(0) STEP(1) STEP(2) STEP(3) STEP(4) STEP(5)
        if (gi < 30) {
            STAGE(gi + 2)
            asm volatile("s_waitcnt vmcnt(8)" ::: "memory");
        } else if (gi == 30) {
            asm volatile("s_waitcnt vmcnt(0)" ::: "memory");   // group 31 resident
        }
        STEP(6) STEP(7)
    }
#undef STEP
#undef STAGE

    asm volatile("s_waitcnt lgkmcnt(0)" ::: "memory");
    __builtin_amdgcn_sched_barrier(0);

    // Phase 2: y[p] = sum over my t-slice {t = 8*tb + j} of sum_u h[t][u]*W10[t*6+u][p]
    float yl[10];
#pragma unroll
    for (int p = 0; p < 10; ++p) yl[p] = 0.0f;

#pragma unroll 2
    for (int tb = 0; tb < 32; ++tb) {
        const int t = tb * 8 + j;
        const float* hb = h_lds + (t << 6) + (grp << 3);
        const float2 h01 = *(const float2*)(hb + 0);
        const float2 h23 = *(const float2*)(hb + 2);
        const float2 h45 = *(const float2*)(hb + 4);
        const float* wr = W10 + (size_t)t * 60;
#define ACCU(U, HV) { \
        const float2 w0 = *(const float2*)(wr + (U) * 10 + 0); \
        const float2 w1 = *(const float2*)(wr + (U) * 10 + 2); \
        const float2 w2 = *(const float2*)(wr + (U) * 10 + 4); \
        const float2 w3 = *(const float2*)(wr + (U) * 10 + 6); \
        const float2 w4 = *(const float2*)(wr + (U) * 10 + 8); \
        yl[0] = fmaf(HV, w0.x, yl[0]); yl[1] = fmaf(HV, w0.y, yl[1]); \
        yl[2] = fmaf(HV, w1.x, yl[2]); yl[3] = fmaf(HV, w1.y, yl[3]); \
        yl[4] = fmaf(HV, w2.x, yl[4]); yl[5] = fmaf(HV, w2.y, yl[5]); \
        yl[6] = fmaf(HV, w3.x, yl[6]); yl[7] = fmaf(HV, w3.y, yl[7]); \
        yl[8] = fmaf(HV, w4.x, yl[8]); yl[9] = fmaf(HV, w4.y, yl[9]); }
        ACCU(0, h01.x) ACCU(1, h01.y) ACCU(2, h23.x)
        ACCU(3, h23.y) ACCU(4, h45.x) ACCU(5, h45.y)
#undef ACCU
    }

#pragma unroll
    for (int p = 0; p < 10; ++p) {
        float v = yl[p];
        v += dppf<DPP_XOR1>(v);
        v += dppf<DPP_XOR2>(v);
        v += dpp_xor4(v);
        yl[p] = v;
    }

    float o8 = bo[j];
#pragma unroll
    for (int p = 0; p < 10; ++p) o8 = fmaf(yl[p] + b10[p], Wo[p * 8 + j], o8);
    out[(size_t)b * 8 + j] = o8;
}

extern "C" void kernel_launch(void* const* d_in, const int* in_sizes, int n_in,
                              void* d_out, int out_size, void* d_ws, size_t ws_size,
                              hipStream_t stream) {
    const float* x   = (const float*)d_in[0];
    const float* Wa  = (const float*)d_in[1];
    const float* ba  = (const float*)d_in[2];
    const float* Wl  = (const float*)d_in[3];
    const float* Ul  = (const float*)d_in[4];
    const float* bl  = (const float*)d_in[5];
    const float* W10 = (const float*)d_in[6];
    const float* b10 = (const float*)d_in[7];
    const float* Wo  = (const float*)d_in[8];
    const float* bo  = (const float*)d_in[9];
    float* out = (float*)d_out;
    float* xz  = (float*)d_ws;   // BB*TT*24*4 = 96 MiB

    hipLaunchKernelGGL(k_attn_xz, dim3(BB * TT * 4 / 512), dim3(256), 0, stream,
                       x, Wa, ba, Wl, bl, xz);
    hipLaunchKernelGGL(k_scan, dim3(BB / 8), dim3(64), 0, stream,
                       xz, Ul, W10, b10, Wo, bo, out);
}

// Round 20
// 108.139 us; speedup vs baseline: 1.2809x; 1.2444x over previous
//
#include <hip/hip_runtime.h>

#define BB 4096
#define TT 256
#define FF 32
#define HH 6

#define DPP_XOR1 0xB1   // quad_perm(1,0,3,2)
#define DPP_XOR2 0x4E   // quad_perm(2,3,0,1)
#define DPP_XOR3 0x1B   // quad_perm(3,2,1,0)
#define DPP_HALF 0x141  // row_half_mirror = xor 7 within 8-lane half-rows

__device__ __forceinline__ float fast_rcp(float x) { return __builtin_amdgcn_rcpf(x); }
__device__ __forceinline__ float sigmoidf(float x) { return fast_rcp(1.0f + __expf(-x)); }

template <int CTRL>
__device__ __forceinline__ float dppf(float x) {
    return __int_as_float(__builtin_amdgcn_update_dpp(
        0, __float_as_int(x), CTRL, 0xF, 0xF, true));
}
__device__ __forceinline__ float dpp_xor4(float x) {
    return dppf<DPP_HALF>(dppf<DPP_XOR3>(x));
}

typedef const __attribute__((address_space(1))) void* gas_ptr;
typedef __attribute__((address_space(3))) void* las_ptr;
__device__ __forceinline__ void gl_lds16(const float* g, float* l) {
    __builtin_amdgcn_global_load_lds((gas_ptr)g, (las_ptr)l, 16, 0, 0);
}

typedef short short8 __attribute__((ext_vector_type(8)));
typedef float f32x4 __attribute__((ext_vector_type(4)));
#define MFMA16(A, B, C) __builtin_amdgcn_mfma_f32_16x16x32_bf16(A, B, C, 0, 0, 0)

__device__ __forceinline__ unsigned short rne_bf16(float f) {
    unsigned u = __float_as_uint(f);
    u = u + 0x7FFFu + ((u >> 16) & 1u);
    return (unsigned short)(u >> 16);
}
__device__ __forceinline__ float bf16f(unsigned short s) {
    return __uint_as_float(((unsigned)s) << 16);
}

// K1 v4 (MFMA): 16 items per wave-iteration via mfma_f32_16x16x32_bf16 with
// 3-term split-bf16 (fp32-accurate). Weights resident in VGPRs as B-frags.
// A/B k-pattern: k = 4*(lane>>4) + (e&3) + 16*(e>>2); row/col = lane&15.
// C/D: col = lane&15, row = 4*(lane>>4) + reg (m89-verified).
// Softmax row-sum via width-16 shfl_xor; e and z bounced through per-wave LDS.
#define K1_ITERS 8
__global__ __launch_bounds__(256, 4) void k_attn_xz(
    const float* __restrict__ x, const float* __restrict__ Wa, const float* __restrict__ ba,
    const float* __restrict__ Wl, const float* __restrict__ bl, float* __restrict__ xz)
{
    const int lane = threadIdx.x & 63;
    const int wid = threadIdx.x >> 6;
    const int l15 = lane & 15;
    const int g = lane >> 4;

    __shared__ __align__(16) float ebuf[4][16 * 36];   // per-wave staging (2.25KB each)
    float* my = ebuf[wid];

    // persistent B-frags: Wa tiles (cols 0-15, 16-31), Wl tiles (cols 0-15, 16-23+pad)
    short8 waH0, waL0, waH1, waL1, wlH0, wlL0, wlH1, wlL1;
#pragma unroll
    for (int e = 0; e < 8; ++e) {
        const int k = 4 * g + (e & 3) + 16 * (e >> 2);
        {
            const float w0 = Wa[k * 32 + l15];
            const unsigned short h0 = rne_bf16(w0);
            waH0[e] = (short)h0; waL0[e] = (short)rne_bf16(w0 - bf16f(h0));
            const float w1 = Wa[k * 32 + 16 + l15];
            const unsigned short h1 = rne_bf16(w1);
            waH1[e] = (short)h1; waL1[e] = (short)rne_bf16(w1 - bf16f(h1));
        }
        {
            const float v0 = Wl[k * 24 + l15];
            const unsigned short h0 = rne_bf16(v0);
            wlH0[e] = (short)h0; wlL0[e] = (short)rne_bf16(v0 - bf16f(h0));
            const float v1 = (l15 < 8) ? Wl[k * 24 + 16 + l15] : 0.0f;
            const unsigned short h1 = rne_bf16(v1);
            wlH1[e] = (short)h1; wlL1[e] = (short)rne_bf16(v1 - bf16f(h1));
        }
    }
    const float ba0 = ba[l15];
    const float ba1 = ba[16 + l15];
    const int c1 = 16 + l15;
    const float bl0 = bl[l15];                       // col c0 = l15 < 16
    const float bl1 = (l15 < 8) ? bl[c1] : 0.0f;     // col c1 valid < 24
    const int off0 = (l15 % 6) * 4 + l15 / 6;        // [unit][gate] offset for col c0
    const int off1 = (c1 % 6) * 4 + c1 / 6;          // for col c1 (l15<8 only)

    const int gw = blockIdx.x * 4 + wid;

    for (int it = 0; it < K1_ITERS; ++it) {
        const int ibase = (gw * K1_ITERS + it) * 16;
        // load x rows in A layout: row = l15, k chunks at 4g and 16+4g
        const float* xr = x + (size_t)(ibase + l15) * FF + 4 * g;
        const float4 xc0 = *(const float4*)(xr);
        const float4 xc1 = *(const float4*)(xr + 16);
        float xa[8] = {xc0.x, xc0.y, xc0.z, xc0.w, xc1.x, xc1.y, xc1.z, xc1.w};
        short8 ah, al;
#pragma unroll
        for (int e = 0; e < 8; ++e) {
            const unsigned short h = rne_bf16(xa[e]);
            ah[e] = (short)h;
            al[e] = (short)rne_bf16(xa[e] - bf16f(h));
        }

        // scores: 3-term split per col-tile
        f32x4 s0 = {0.f, 0.f, 0.f, 0.f}, s1 = {0.f, 0.f, 0.f, 0.f};
        s0 = MFMA16(al, waH0, s0); s0 = MFMA16(ah, waL0, s0); s0 = MFMA16(ah, waH0, s0);
        s1 = MFMA16(al, waH1, s1); s1 = MFMA16(ah, waL1, s1); s1 = MFMA16(ah, waH1, s1);

        // exp (no max-sub, verified) + per-item row-sum (16-lane xor reduce)
        float e0[4], e1[4], rs[4];
#pragma unroll
        for (int r = 0; r < 4; ++r) {
            e0[r] = __expf(s0[r] + ba0);
            e1[r] = __expf(s1[r] + ba1);
            float t = e0[r] + e1[r];
            t += __shfl_xor(t, 1);
            t += __shfl_xor(t, 2);
            t += __shfl_xor(t, 4);
            t += __shfl_xor(t, 8);
            rs[r] = fast_rcp(t);
        }

        // e: C layout -> LDS (stride 36) -> re-read in A layout
#pragma unroll
        for (int r = 0; r < 4; ++r) {
            my[(4 * g + r) * 36 + l15] = e0[r];
            my[(4 * g + r) * 36 + 16 + l15] = e1[r];
        }
        const float* er = my + l15 * 36 + 4 * g;
        const float4 ec0 = *(const float4*)(er);
        const float4 ec1 = *(const float4*)(er + 16);
        const float ea[8] = {ec0.x, ec0.y, ec0.z, ec0.w, ec1.x, ec1.y, ec1.z, ec1.w};

        short8 ph, pl;
#pragma unroll
        for (int e = 0; e < 8; ++e) {
            const float p = xa[e] * ea[e];
            const unsigned short h = rne_bf16(p);
            ph[e] = (short)h;
            pl[e] = (short)rne_bf16(p - bf16f(h));
        }

        f32x4 z0 = {0.f, 0.f, 0.f, 0.f}, z1 = {0.f, 0.f, 0.f, 0.f};
        z0 = MFMA16(pl, wlH0, z0); z0 = MFMA16(ph, wlL0, z0); z0 = MFMA16(ph, wlH0, z0);
        z1 = MFMA16(pl, wlH1, z1); z1 = MFMA16(ph, wlL1, z1); z1 = MFMA16(ph, wlH1, z1);

        // z: scale by 1/sum (row distribution matches C layout), +bl,
        // scatter to LDS compact [item][unit*4+gate], then coalesced store
#pragma unroll
        for (int r = 0; r < 4; ++r) {
            my[(4 * g + r) * 24 + off0] = fmaf(z0[r], rs[r], bl0);
            if (l15 < 8) my[(4 * g + r) * 24 + off1] = fmaf(z1[r], rs[r], bl1);
        }
        float* op = xz + (size_t)ibase * 24 + lane * 6;
        const float* zr = my + lane * 6;
        const float2 o0 = *(const float2*)(zr);
        const float2 o1 = *(const float2*)(zr + 2);
        const float2 o2 = *(const float2*)(zr + 4);
        *(float2*)(op) = o0;
        *(float2*)(op + 2) = o1;
        *(float2*)(op + 4) = o2;
    }
}

// One LSTM step (defer-max c-softmax, verified). Returns hn.
__device__ __forceinline__ float chain_step(
    float hl[8], float& c, float& r2,
    const float Ui[8], const float Uf[8], const float Ug[8], const float Uo[8],
    const float4 z4, const bool real)
{
    float di0 = hl[0]*Ui[0], di1 = hl[4]*Ui[4];
    float df0 = hl[0]*Uf[0], df1 = hl[4]*Uf[4];
    float dg0 = hl[0]*Ug[0], dg1 = hl[4]*Ug[4];
    float dq0 = hl[0]*Uo[0], dq1 = hl[4]*Uo[4];
#pragma unroll
    for (int m = 1; m < 4; ++m) {
        di0 = fmaf(hl[m], Ui[m], di0); di1 = fmaf(hl[m+4], Ui[m+4], di1);
        df0 = fmaf(hl[m], Uf[m], df0); df1 = fmaf(hl[m+4], Uf[m+4], df1);
        dg0 = fmaf(hl[m], Ug[m], dg0); dg1 = fmaf(hl[m+4], Ug[m+4], dg1);
        dq0 = fmaf(hl[m], Uo[m], dq0); dq1 = fmaf(hl[m+4], Uo[m+4], dq1);
    }
    const float zi = fmaf(di0 + di1, r2, z4.x);
    const float zf = fmaf(df0 + df1, r2, z4.y);
    const float zg = fmaf(dg0 + dg1, r2, z4.z);
    const float zo = fmaf(dq0 + dq1, r2, z4.w);

    const float iv = sigmoidf(zi);
    const float fv = sigmoidf(zf);
    const float ov = sigmoidf(zo);

    const float eg = real ? __expf(zg) : 0.0f;
    float s1 = eg;
    s1 += dppf<DPP_XOR1>(s1);
    s1 += dppf<DPP_XOR2>(s1);
    s1 += dpp_xor4(s1);
    c = fmaf(fv, c, (iv * eg) * fast_rcp(s1));

    const float ec = real ? __expf(c) : 0.0f;   // defer-max (uniform exp(-m) cancels)
    float s2 = ec;
    s2 += dppf<DPP_XOR1>(s2);
    s2 += dppf<DPP_XOR2>(s2);
    s2 += dpp_xor4(s2);

    const float ovec = ov * ec;
    hl[0] = ovec;
    hl[1] = dppf<DPP_XOR1>(ovec);
    hl[2] = dppf<DPP_XOR2>(ovec);
    hl[3] = dppf<DPP_XOR3>(ovec);
    const float h7 = dppf<DPP_HALF>(ovec);
    hl[7] = h7;
    hl[6] = dppf<DPP_XOR1>(h7);
    hl[5] = dppf<DPP_XOR2>(h7);
    hl[4] = dppf<DPP_XOR3>(h7);
    r2 = fast_rcp(s2);
    return ovec * r2;
}

// K2 (byte-identical to R17-R19, verified): deferred-y scan + parallel dense(10).
__global__ __launch_bounds__(64, 1) void k_scan(
    const float* __restrict__ xz, const float* __restrict__ Ul,
    const float* __restrict__ W10, const float* __restrict__ b10,
    const float* __restrict__ Wo, const float* __restrict__ bo,
    float* __restrict__ out)
{
    const int lane = threadIdx.x;
    const int j = lane & 7;
    const int grp = lane >> 3;
    const int b = blockIdx.x * 8 + grp;
    const bool real = (j < HH);

    __shared__ __align__(1024) float ring[16 * 256];   // 16 steps x 1KB
    __shared__ __align__(16) float h_lds[TT * 64];     // 64KB: h[t][lane]

    float Ui[8], Uf[8], Ug[8], Uo[8];
#pragma unroll
    for (int m = 0; m < 8; ++m) {
        const int src = j ^ m;
        const bool ok = real && (src < HH);
        const float* row = Ul + (ok ? src : 0) * 24;
        Ui[m] = ok ? row[0  + j] : 0.0f;
        Uf[m] = ok ? row[6  + j] : 0.0f;
        Ug[m] = ok ? row[12 + j] : 0.0f;
        Uo[m] = ok ? row[18 + j] : 0.0f;
    }

    float hl[8];
    float r2 = 1.0f, c = 0.0f;
#pragma unroll
    for (int m = 0; m < 8; ++m) hl[m] = 0.0f;

    const float* gsrc = xz + (size_t)b * (TT * 24) + j * 4;

#define STAGE(G) { \
        const float* s_ = gsrc + (size_t)((G) * 8) * 24; \
        float* lb_ = ring + (((G) * 8) & 15) * 256; \
        _Pragma("unroll") \
        for (int k_ = 0; k_ < 8; ++k_) gl_lds16(s_ + k_ * 24, lb_ + k_ * 256); }

    STAGE(0) STAGE(1)
    asm volatile("s_waitcnt vmcnt(8)" ::: "memory");   // group 0 resident

    float4 zcur = *(const float4*)(ring + 0 * 256 + lane * 4);
    float4 zn1  = *(const float4*)(ring + 1 * 256 + lane * 4);

#define STEP(K) { \
        const float4 zn2 = *(const float4*)(ring + (((sb + (K) + 2) & 15) << 8) + lane * 4); \
        const float hn = chain_step(hl, c, r2, Ui, Uf, Ug, Uo, zcur, real); \
        h_lds[((t0 + (K)) << 6) + lane] = hn; \
        zcur = zn1; zn1 = zn2; }

#pragma unroll 1
    for (int gi = 0; gi < 32; ++gi) {
        const int t0 = gi * 8;
        const int sb = (gi & 1) * 8;
        STEP(0) STEP(1) STEP(2) STEP(3) STEP(4) STEP(5)
        if (gi < 30) {
            STAGE(gi + 2)
            asm volatile("s_waitcnt vmcnt(8)" ::: "memory");
        } else if (gi == 30) {
            asm volatile("s_waitcnt vmcnt(0)" ::: "memory");   // group 31 resident
        }
        STEP(6) STEP(7)
    }
#undef STEP
#undef STAGE

    asm volatile("s_waitcnt lgkmcnt(0)" ::: "memory");
    __builtin_amdgcn_sched_barrier(0);

    // Phase 2: y[p] = sum over my t-slice {t = 8*tb + j} of sum_u h[t][u]*W10[t*6+u][p]
    float yl[10];
#pragma unroll
    for (int p = 0; p < 10; ++p) yl[p] = 0.0f;

#pragma unroll 2
    for (int tb = 0; tb < 32; ++tb) {
        const int t = tb * 8 + j;
        const float* hb = h_lds + (t << 6) + (grp << 3);
        const float2 h01 = *(const float2*)(hb + 0);
        const float2 h23 = *(const float2*)(hb + 2);
        const float2 h45 = *(const float2*)(hb + 4);
        const float* wr = W10 + (size_t)t * 60;
#define ACCU(U, HV) { \
        const float2 w0 = *(const float2*)(wr + (U) * 10 + 0); \
        const float2 w1 = *(const float2*)(wr + (U) * 10 + 2); \
        const float2 w2 = *(const float2*)(wr + (U) * 10 + 4); \
        const float2 w3 = *(const float2*)(wr + (U) * 10 + 6); \
        const float2 w4 = *(const float2*)(wr + (U) * 10 + 8); \
        yl[0] = fmaf(HV, w0.x, yl[0]); yl[1] = fmaf(HV, w0.y, yl[1]); \
        yl[2] = fmaf(HV, w1.x, yl[2]); yl[3] = fmaf(HV, w1.y, yl[3]); \
        yl[4] = fmaf(HV, w2.x, yl[4]); yl[5] = fmaf(HV, w2.y, yl[5]); \
        yl[6] = fmaf(HV, w3.x, yl[6]); yl[7] = fmaf(HV, w3.y, yl[7]); \
        yl[8] = fmaf(HV, w4.x, yl[8]); yl[9] = fmaf(HV, w4.y, yl[9]); }
        ACCU(0, h01.x) ACCU(1, h01.y) ACCU(2, h23.x)
        ACCU(3, h23.y) ACCU(4, h45.x) ACCU(5, h45.y)
#undef ACCU
    }

#pragma unroll
    for (int p = 0; p < 10; ++p) {
        float v = yl[p];
        v += dppf<DPP_XOR1>(v);
        v += dppf<DPP_XOR2>(v);
        v += dpp_xor4(v);
        yl[p] = v;
    }

    float o8 = bo[j];
#pragma unroll
    for (int p = 0; p < 10; ++p) o8 = fmaf(yl[p] + b10[p], Wo[p * 8 + j], o8);
    out[(size_t)b * 8 + j] = o8;
}

extern "C" void kernel_launch(void* const* d_in, const int* in_sizes, int n_in,
                              void* d_out, int out_size, void* d_ws, size_t ws_size,
                              hipStream_t stream) {
    const float* x   = (const float*)d_in[0];
    const float* Wa  = (const float*)d_in[1];
    const float* ba  = (const float*)d_in[2];
    const float* Wl  = (const float*)d_in[3];
    const float* Ul  = (const float*)d_in[4];
    const float* bl  = (const float*)d_in[5];
    const float* W10 = (const float*)d_in[6];
    const float* b10 = (const float*)d_in[7];
    const float* Wo  = (const float*)d_in[8];
    const float* bo  = (const float*)d_in[9];
    float* out = (float*)d_out;
    float* xz  = (float*)d_ws;   // BB*TT*24*4 = 96 MiB

    // waves = BB*TT / (16 items * K1_ITERS) = 8192 -> 2048 blocks of 4 waves
    hipLaunchKernelGGL(k_attn_xz, dim3(BB * TT / (16 * K1_ITERS * 4)), dim3(256), 0, stream,
                       x, Wa, ba, Wl, bl, xz);
    hipLaunchKernelGGL(k_scan, dim3(BB / 8), dim3(64), 0, stream,
                       xz, Ul, W10, b10, Wo, bo, out);
}